// Round 5
// baseline (197.895 us; speedup 1.0000x reference)
//
#include <hip/hip_runtime.h>
#include <hip/hip_bf16.h>

#define S_LEN 4096
#define B_SZ 2
#define DM 1024
#define NH 16
#define DH 64

typedef __attribute__((ext_vector_type(8))) short short8;
typedef __attribute__((ext_vector_type(4))) float f32x4;

__device__ __forceinline__ ushort f2b(float f) {
  union { __hip_bfloat16 b; ushort u; } cv;
  cv.b = __float2bfloat16(f);
  return cv.u;
}

__device__ __forceinline__ short8 pack8(float4 a, float4 b) {
  short8 r;
  r[0] = (short)f2b(a.x); r[1] = (short)f2b(a.y);
  r[2] = (short)f2b(a.z); r[3] = (short)f2b(a.w);
  r[4] = (short)f2b(b.x); r[5] = (short)f2b(b.y);
  r[6] = (short)f2b(b.z); r[7] = (short)f2b(b.w);
  return r;
}

__device__ __forceinline__ void glds16(const ushort* g, ushort* l) {
  __builtin_amdgcn_global_load_lds(
      (const __attribute__((address_space(1))) void*)g,
      (__attribute__((address_space(3))) void*)l, 16, 0, 0);
}

// swizzled LDS access: XOR row bits 0-2 into byte-col bits 4-6 (both sides)
__device__ __forceinline__ short8 ldsrd(const ushort* base, int row, int cb) {
  const int pcb = cb ^ ((row & 7) << 4);
  return *reinterpret_cast<const short8*>(
      reinterpret_cast<const char*>(base) + row * 128 + pcb);
}
__device__ __forceinline__ void ldswr(ushort* base, int row, int cb, short8 v) {
  const int pcb = cb ^ ((row & 7) << 4);
  *reinterpret_cast<short8*>(reinterpret_cast<char*>(base) + row * 128 + pcb) = v;
}

// ---------------- fused-convert pipelined bt-GEMM ----------------
// C[m][n] = sum_k A[m][k]*W[n][k].  BM=256, BN=128, BK=64, 512 threads.
// Staging is reg-path: global (f32 or bf16) -> VGPR -> cvt -> swizzled ds_write.
// 2 LDS bufs; iter kt: read buf[kt&1]; mid-iter write tile kt+1 -> buf^1 and
// issue tile kt+2's global loads (T14 split: ~1 full iter of latency cover).
// Raw s_barrier + lgkmcnt(0) only -- vmem NEVER drains (compiler inserts
// counted vmcnt before the cvt ops that consume the loaded regs).
// MODE 0: QKV fused, A=f32 (q/k/v), W=f32; V written transposed.
// MODE 2: A=bf16 (Ao), W=f32 (wo), out f32.
template <int MODE>
__launch_bounds__(512, 1)
__global__ void gemmP(const float* __restrict__ Af0, const float* __restrict__ Af1,
                      const float* __restrict__ Af2, const ushort* __restrict__ Abf,
                      const float* __restrict__ W0f, const float* __restrict__ W1f,
                      const float* __restrict__ W2f,
                      void* __restrict__ O0, void* __restrict__ O1,
                      void* __restrict__ O2) {
  __shared__ ushort As[2][16384];  // 256x64 bf16 per buf (64 KB)
  __shared__ ushort Bs[2][8192];   // 128x64 bf16 per buf (32 KB)
  const int tid = threadIdx.x;
  const int lane = tid & 63, w = tid >> 6;
  const int wm = w >> 1, wn = w & 1;
  const int g = lane >> 4, lr = lane & 15;
  const int m0 = blockIdx.x * 256;
  const int ysel = (MODE == 0) ? (blockIdx.y >> 3) : 0;
  const float* Af = (MODE == 0) ? (ysel == 0 ? Af0 : ysel == 1 ? Af1 : Af2) : Af0;
  const float* Wf = (MODE == 0) ? (ysel == 0 ? W0f : ysel == 1 ? W1f : W2f) : W0f;
  const int n0 = ((MODE == 0) ? (blockIdx.y & 7) : blockIdx.y) * 128;

  // staging geometry
  const int arow = tid >> 1, ahalf = tid & 1;  // A: 256 rows x 2 col-halves(32)
  const int wrow = tid >> 2, wqtr = tid & 3;   // W: 128 rows x 4 col-qtrs(16)

  float4 ar[8];
  float4 wr4[4];
  short8 ab[4];

#define LOADS(t)                                                              \
  {                                                                           \
    const int kq = (t) * 64;                                                  \
    if (MODE == 0) {                                                          \
      const float* ap = Af + (size_t)(m0 + arow) * DM + kq + ahalf * 32;      \
      _Pragma("unroll")                                                       \
      for (int j = 0; j < 8; j++)                                             \
        ar[j] = *reinterpret_cast<const float4*>(ap + j * 4);                 \
    } else {                                                                  \
      const ushort* ap = Abf + (size_t)(m0 + arow) * DM + kq + ahalf * 32;    \
      _Pragma("unroll")                                                       \
      for (int j = 0; j < 4; j++)                                             \
        ab[j] = *reinterpret_cast<const short8*>(ap + j * 8);                 \
    }                                                                         \
    const float* wp = Wf + (size_t)(n0 + wrow) * DM + kq + wqtr * 16;         \
    _Pragma("unroll")                                                         \
    for (int j = 0; j < 4; j++)                                               \
      wr4[j] = *reinterpret_cast<const float4*>(wp + j * 4);                  \
  }
#define DSW(b)                                                                \
  {                                                                           \
    _Pragma("unroll")                                                         \
    for (int j = 0; j < 4; j++) {                                             \
      short8 v;                                                               \
      if (MODE == 0) v = pack8(ar[2 * j], ar[2 * j + 1]);                     \
      else           v = ab[j];                                               \
      ldswr(As[b], arow, ahalf * 64 + j * 16, v);                             \
    }                                                                         \
    _Pragma("unroll")                                                         \
    for (int j = 0; j < 2; j++)                                               \
      ldswr(Bs[b], wrow, wqtr * 32 + j * 16, pack8(wr4[2 * j], wr4[2 * j + 1])); \
  }

  f32x4 acc[4][4] = {};
  short8 af[4][2], b0[2][2], b1[2][2];

  // prologue: tile0 -> regs -> buf0; tile1 -> regs (stays in flight)
  LOADS(0);
  DSW(0);
  LOADS(1);
  asm volatile("s_waitcnt lgkmcnt(0)" ::: "memory");
  __builtin_amdgcn_sched_barrier(0);
  __builtin_amdgcn_s_barrier();
  __builtin_amdgcn_sched_barrier(0);

  for (int kt = 0; kt < 16; ++kt) {
    const int cur = kt & 1;
    const ushort* Ab = &As[cur][0];
    const ushort* Bb = &Bs[cur][0];
    // all 16 frag reads from current buf
#pragma unroll
    for (int m = 0; m < 4; m++)
#pragma unroll
      for (int kk = 0; kk < 2; kk++)
        af[m][kk] = ldsrd(Ab, wm * 64 + m * 16 + lr, kk * 64 + g * 16);
#pragma unroll
    for (int n = 0; n < 2; n++)
#pragma unroll
      for (int kk = 0; kk < 2; kk++) {
        b0[n][kk] = ldsrd(Bb, wn * 64 + n * 16 + lr, kk * 64 + g * 16);
        b1[n][kk] = ldsrd(Bb, wn * 64 + 32 + n * 16 + lr, kk * 64 + g * 16);
      }
    __builtin_amdgcn_sched_barrier(0);
    __builtin_amdgcn_s_setprio(1);
#pragma unroll
    for (int m = 0; m < 4; m++)
#pragma unroll
      for (int n = 0; n < 2; n++)
#pragma unroll
        for (int kk = 0; kk < 2; kk++)
          acc[m][n] = __builtin_amdgcn_mfma_f32_16x16x32_bf16(af[m][kk], b0[n][kk],
                                                              acc[m][n], 0, 0, 0);
    __builtin_amdgcn_s_setprio(0);
    __builtin_amdgcn_sched_barrier(0);
    // write tile kt+1 (regs -> buf^1), then issue tile kt+2 loads
    if (kt < 15) { DSW(cur ^ 1); }
    if (kt < 14) { LOADS(kt + 2); }
    __builtin_amdgcn_sched_barrier(0);
    __builtin_amdgcn_s_setprio(1);
#pragma unroll
    for (int m = 0; m < 4; m++)
#pragma unroll
      for (int n = 0; n < 2; n++)
#pragma unroll
        for (int kk = 0; kk < 2; kk++)
          acc[m][2 + n] = __builtin_amdgcn_mfma_f32_16x16x32_bf16(af[m][kk], b1[n][kk],
                                                                  acc[m][2 + n], 0, 0, 0);
    __builtin_amdgcn_s_setprio(0);
    asm volatile("s_waitcnt lgkmcnt(0)" ::: "memory");
    __builtin_amdgcn_sched_barrier(0);
    __builtin_amdgcn_s_barrier();
    __builtin_amdgcn_sched_barrier(0);
  }
#undef LOADS
#undef DSW

  // ---- epilogue ----
  const int colB = n0 + wn * 64;
#pragma unroll
  for (int m = 0; m < 4; ++m) {
    const int row0 = m0 + wm * 64 + m * 16 + g * 4;
#pragma unroll
    for (int n = 0; n < 4; ++n) {
      const int col = colB + n * 16 + lr;
      if (MODE == 2) {
#pragma unroll
        for (int r = 0; r < 4; r++)
          reinterpret_cast<float*>(O0)[(size_t)(row0 + r) * DM + col] = acc[m][n][r];
      } else if (ysel == 0 || ysel == 1) {
        ushort* O = reinterpret_cast<ushort*>(ysel == 0 ? O0 : O1);
#pragma unroll
        for (int r = 0; r < 4; r++)
          O[(size_t)(row0 + r) * DM + col] = f2b(acc[m][n][r]);
      } else {
        // V transposed: [B][H][DH][S], 4 consecutive s -> ushort4
        const int b = row0 >> 12, s0 = row0 & 4095;
        const int h = col >> 6, dk = col & 63;
        ushort4 o;
        o.x = f2b(acc[m][n][0]); o.y = f2b(acc[m][n][1]);
        o.z = f2b(acc[m][n][2]); o.w = f2b(acc[m][n][3]);
        *reinterpret_cast<ushort4*>(
            reinterpret_cast<ushort*>(O2) +
            (((size_t)(b * NH + h) * DH + dk) << 12) + s0) = o;
      }
    }
  }
}

// ---------------- local attention (window |i-j|<=128) ----------------
// Double-buffered K/V staging with counted vmcnt; raw barriers (no vm drain).
__global__ void attn_local(const ushort* __restrict__ Qp, const ushort* __restrict__ Kp,
                           const ushort* __restrict__ Vt, ushort* __restrict__ Ao) {
  __shared__ ushort Ks[2][4096];
  __shared__ ushort Vs[2][4096];
  __shared__ ushort Ps[4][16 * 72];
  const int tid = threadIdx.x;
  const int lane = tid & 63;
  const int w = tid >> 6;
  const int g = lane >> 4, lr = lane & 15;
  const int bh = blockIdx.y, b = bh >> 4, h = bh & 15;
  const int q0 = blockIdx.x * 64;

  const int qrow = q0 + w * 16 + lr;
  const ushort* qptr = Qp + ((size_t)b * S_LEN + qrow) * DM + h * DH;
  short8 qf[2];
  qf[0] = *reinterpret_cast<const short8*>(qptr + g * 8);
  qf[1] = *reinterpret_cast<const short8*>(qptr + 32 + g * 8);

  float m_r[4], l_r[4];
  f32x4 acc_o[4] = {};
#pragma unroll
  for (int r = 0; r < 4; r++) { m_r[r] = -1e30f; l_r[r] = 0.f; }

  const int sr = tid >> 3;
  const int scb = (tid & 7) * 16;

  const int t_lo = q0 >= 128 ? q0 - 128 : 0;
  const int t_hi = (q0 + 192) <= S_LEN ? (q0 + 192) : S_LEN;

#define STAGE(bb, kk0)                                                        \
  {                                                                           \
    _Pragma("unroll")                                                         \
    for (int i = 0; i < 2; i++) {                                             \
      const int row = i * 32 + sr;                                            \
      const int cb = scb ^ ((row & 7) << 4);                                  \
      glds16(Kp + ((size_t)b * S_LEN + (kk0) + row) * DM + h * DH + cb / 2,   \
             &Ks[bb][i * 2048 + w * 512]);                                    \
      glds16(Vt + (((size_t)bh * DH + row) << 12) + (kk0) + cb / 2,           \
             &Vs[bb][i * 2048 + w * 512]);                                    \
    }                                                                         \
  }

  STAGE(0, t_lo);

  int it = 0;
  for (int k0 = t_lo; k0 < t_hi; k0 += 64, ++it) {
    const int cur = it & 1;
    const bool pf = (k0 + 64 < t_hi);
    if (pf) {
      STAGE(cur ^ 1, k0 + 64);
      asm volatile("s_waitcnt vmcnt(4)" ::: "memory");
    } else {
      asm volatile("s_waitcnt vmcnt(0)" ::: "memory");
    }
    __builtin_amdgcn_sched_barrier(0);
    __builtin_amdgcn_s_barrier();
    __builtin_amdgcn_sched_barrier(0);

    f32x4 sc[4] = {};
#pragma unroll
    for (int kk = 0; kk < 2; kk++) {
#pragma unroll
      for (int nt = 0; nt < 4; nt++) {
        const int kr = nt * 16 + lr;
        const int cb = (kk * 64 + g * 16) ^ ((kr & 7) << 4);
        short8 kf = *reinterpret_cast<const short8*>(
            reinterpret_cast<const char*>(&Ks[cur][0]) + kr * 128 + cb);
        sc[nt] = __builtin_amdgcn_mfma_f32_16x16x32_bf16(qf[kk], kf, sc[nt], 0, 0, 0);
      }
    }
    // scale (+ mask only on the 2 edge tiles) + row max
    const bool edge = (k0 < q0 - 64) || (k0 > q0 + 64);
    float mx[4] = {-1e30f, -1e30f, -1e30f, -1e30f};
    if (edge) {
#pragma unroll
      for (int nt = 0; nt < 4; nt++) {
        const int key = k0 + nt * 16 + lr;
#pragma unroll
        for (int r = 0; r < 4; r++) {
          const int qr = q0 + w * 16 + g * 4 + r;
          int d = qr - key; d = d < 0 ? -d : d;
          float s = (d <= 128) ? sc[nt][r] * 0.125f : -1e9f;
          sc[nt][r] = s;
          mx[r] = fmaxf(mx[r], s);
        }
      }
    } else {
#pragma unroll
      for (int nt = 0; nt < 4; nt++)
#pragma unroll
        for (int r = 0; r < 4; r++) {
          const float s = sc[nt][r] * 0.125f;
          sc[nt][r] = s;
          mx[r] = fmaxf(mx[r], s);
        }
    }
#pragma unroll
    for (int r = 0; r < 4; r++) {
      mx[r] = fmaxf(mx[r], __shfl_xor(mx[r], 1));
      mx[r] = fmaxf(mx[r], __shfl_xor(mx[r], 2));
      mx[r] = fmaxf(mx[r], __shfl_xor(mx[r], 4));
      mx[r] = fmaxf(mx[r], __shfl_xor(mx[r], 8));
    }
    float fac[4], rs[4];
#pragma unroll
    for (int r = 0; r < 4; r++) {
      const float mn = fmaxf(m_r[r], mx[r]);
      fac[r] = __expf(m_r[r] - mn);
      m_r[r] = mn;
      rs[r] = 0.f;
    }
#pragma unroll
    for (int nt = 0; nt < 4; nt++)
#pragma unroll
      for (int r = 0; r < 4; r++) {
        const float p = __expf(sc[nt][r] - m_r[r]);
        sc[nt][r] = p;
        rs[r] += p;
      }
#pragma unroll
    for (int r = 0; r < 4; r++) {
      rs[r] += __shfl_xor(rs[r], 1);
      rs[r] += __shfl_xor(rs[r], 2);
      rs[r] += __shfl_xor(rs[r], 4);
      rs[r] += __shfl_xor(rs[r], 8);
      l_r[r] = l_r[r] * fac[r] + rs[r];
    }
#pragma unroll
    for (int nt = 0; nt < 4; nt++)
#pragma unroll
      for (int r = 0; r < 4; r++)
        acc_o[nt][r] *= fac[r];

    ushort* myP = Ps[w];
#pragma unroll
    for (int nt = 0; nt < 4; nt++)
#pragma unroll
      for (int r = 0; r < 4; r++)
        myP[(g * 4 + r) * 72 + nt * 16 + lr] = f2b(sc[nt][r]);
    asm volatile("s_waitcnt lgkmcnt(0)" ::: "memory");
    __builtin_amdgcn_sched_barrier(0);

#pragma unroll
    for (int kk = 0; kk < 2; kk++) {
      short8 pf2 = *reinterpret_cast<const short8*>(myP + lr * 72 + kk * 32 + g * 8);
#pragma unroll
      for (int nt = 0; nt < 4; nt++) {
        const int vr = nt * 16 + lr;
        const int cb = (kk * 64 + g * 16) ^ ((vr & 7) << 4);
        short8 vf = *reinterpret_cast<const short8*>(
            reinterpret_cast<const char*>(&Vs[cur][0]) + vr * 128 + cb);
        acc_o[nt] = __builtin_amdgcn_mfma_f32_16x16x32_bf16(pf2, vf, acc_o[nt], 0, 0, 0);
      }
    }
    __builtin_amdgcn_sched_barrier(0);
    __builtin_amdgcn_s_barrier();
    __builtin_amdgcn_sched_barrier(0);
  }
#undef STAGE

  const int qr0 = q0 + w * 16 + g * 4;
  ushort* orow = Ao + (size_t)b * S_LEN * DM + h * DH;
#pragma unroll
  for (int nt = 0; nt < 4; nt++)
#pragma unroll
    for (int r = 0; r < 4; r++)
      orow[(size_t)(qr0 + r) * DM + nt * 16 + lr] = f2b(acc_o[nt][r] / l_r[r]);
}

extern "C" void kernel_launch(void* const* d_in, const int* in_sizes, int n_in,
                              void* d_out, int out_size, void* d_ws, size_t ws_size,
                              hipStream_t stream) {
  const float* q  = (const float*)d_in[0];
  const float* k  = (const float*)d_in[1];
  const float* v  = (const float*)d_in[2];
  const float* wq = (const float*)d_in[3];
  const float* wk = (const float*)d_in[4];
  const float* wv = (const float*)d_in[5];
  const float* wo = (const float*)d_in[6];

  const size_t NX = (size_t)B_SZ * S_LEN * DM;  // 8388608
  if (ws_size < 4 * NX * sizeof(ushort)) return;

  ushort* ws = (ushort*)d_ws;
  ushort* Qp = ws;
  ushort* Kp = Qp + NX;
  ushort* Vt = Kp + NX;
  ushort* Ao = Vt + NX;

  gemmP<0><<<dim3(32, 24), dim3(512), 0, stream>>>(q, k, v, nullptr, wq, wk, wv,
                                                   Qp, Kp, Vt);

  attn_local<<<dim3(64, 32), dim3(256), 0, stream>>>(Qp, Kp, Vt, Ao);

  gemmP<2><<<dim3(32, 8), dim3(512), 0, stream>>>(nullptr, nullptr, nullptr, Ao,
                                                  wo, wo, wo, d_out, d_out, d_out);
}

// Round 6
// 160.349 us; speedup vs baseline: 1.2342x; 1.2342x over previous
//
#include <hip/hip_runtime.h>
#include <hip/hip_bf16.h>

#define S_LEN 4096
#define B_SZ 2
#define DM 1024
#define NH 16
#define DH 64

typedef __attribute__((ext_vector_type(8))) short short8;
typedef __attribute__((ext_vector_type(4))) float f32x4;

__device__ __forceinline__ ushort f2b(float f) {
  union { __hip_bfloat16 b; ushort u; } cv;
  cv.b = __float2bfloat16(f);
  return cv.u;
}

__device__ __forceinline__ void glds16(const ushort* g, ushort* l) {
  __builtin_amdgcn_global_load_lds(
      (const __attribute__((address_space(1))) void*)g,
      (__attribute__((address_space(3))) void*)l, 16, 0, 0);
}

// ---------------- merged fp32 -> bf16 convert ----------------
__global__ void cvt_all(const float* __restrict__ q, const float* __restrict__ k,
                        const float* __restrict__ v, const float* __restrict__ wq,
                        const float* __restrict__ wk, const float* __restrict__ wv,
                        const float* __restrict__ wo, ushort* __restrict__ dst) {
  const int NX4 = 2097152;  // 8M/4
  const int NW4 = 262144;   // 1M/4
  const int total = 3 * NX4 + 4 * NW4;
  for (int i = blockIdx.x * blockDim.x + threadIdx.x; i < total;
       i += gridDim.x * blockDim.x) {
    const float* s;
    int j;
    if (i < NX4) { s = q; j = i; }
    else if (i < 2 * NX4) { s = k; j = i - NX4; }
    else if (i < 3 * NX4) { s = v; j = i - 2 * NX4; }
    else {
      int t = i - 3 * NX4;
      int wsel = t >> 18;
      j = t & (NW4 - 1);
      s = wsel == 0 ? wq : wsel == 1 ? wk : wsel == 2 ? wv : wo;
    }
    float4 val = reinterpret_cast<const float4*>(s)[j];
    ushort4 o;
    o.x = f2b(val.x); o.y = f2b(val.y); o.z = f2b(val.z); o.w = f2b(val.w);
    reinterpret_cast<ushort4*>(dst)[i] = o;
  }
}

// swizzled LDS read: XOR row bits 0-2 into byte-col bits 4-6
__device__ __forceinline__ short8 ldsrd(const ushort* base, int row, int cb) {
  const int pcb = cb ^ ((row & 7) << 4);
  return *reinterpret_cast<const short8*>(
      reinterpret_cast<const char*>(base) + row * 128 + pcb);
}

// ---------------- 3-deep pipelined bt-GEMM ----------------
// C[m][n] = sum_k A[m][k]*W[n][k].  BM=256, BN=128, BK=64, 512 threads.
// 8 waves (wm=w>>1 in 0..3, wn=w&1), per-wave 64x64 output.
// 3 LDS buffers; iteration kt reads buf kt%3, stages tile kt+2 into (kt+2)%3.
// ONE barrier + ONE vmcnt(6) + ONE lgkm drain per K-tile; 32 MFMA run
// uninterrupted. vmcnt never drains below 6 (tile waited on was staged
// 2 iterations earlier).
// MODE 0: QKV fused (blockIdx.y>>3 selects mat; V written transposed).
// MODE 2: f32 out.
template <int MODE>
__launch_bounds__(512, 2)
__global__ void gemmP(const ushort* __restrict__ A0, const ushort* __restrict__ A1,
                      const ushort* __restrict__ A2, const ushort* __restrict__ W0,
                      const ushort* __restrict__ W1, const ushort* __restrict__ W2,
                      void* __restrict__ O0, void* __restrict__ O1,
                      void* __restrict__ O2) {
  __shared__ ushort As[3][16384];  // 256x64 each, 96 KB
  __shared__ ushort Bs[3][8192];   // 128x64 each, 48 KB
  const int tid = threadIdx.x;
  const int lane = tid & 63, w = tid >> 6;
  const int wm = w >> 1, wn = w & 1;
  const int g = lane >> 4, lr = lane & 15;
  const int m0 = blockIdx.x * 256;
  const int ysel = (MODE == 0) ? (blockIdx.y >> 3) : 0;
  const ushort* A = (MODE == 0) ? (ysel == 0 ? A0 : ysel == 1 ? A1 : A2) : A0;
  const ushort* W = (MODE == 0) ? (ysel == 0 ? W0 : ysel == 1 ? W1 : W2) : W0;
  const int n0 = ((MODE == 0) ? (blockIdx.y & 7) : blockIdx.y) * 128;

  // staging geometry: thread -> (row tid>>3, 16B chunk tid&7), pre-swizzled src
  const int row_r = tid >> 3;
  const int cb = ((tid & 7) * 16) ^ ((row_r & 7) << 4);
  const ushort* Asrc = A + (size_t)(m0 + row_r) * DM + (cb >> 1);
  const ushort* Wsrc = W + (size_t)(n0 + row_r) * DM + (cb >> 1);

  // A: 4 segments of 64 rows; B: 2 segments. 6 loads/thread per K-tile.
#define STG_ALL(bs, kt)                                                      \
  { const int kq = (kt) * 64;                                                \
    glds16(Asrc + kq,                        &As[bs][w * 512]);              \
    glds16(Asrc + (size_t)64 * DM + kq,      &As[bs][4096 + w * 512]);       \
    glds16(Asrc + (size_t)128 * DM + kq,     &As[bs][8192 + w * 512]);       \
    glds16(Asrc + (size_t)192 * DM + kq,     &As[bs][12288 + w * 512]);      \
    glds16(Wsrc + kq,                        &Bs[bs][w * 512]);              \
    glds16(Wsrc + (size_t)64 * DM + kq,      &Bs[bs][4096 + w * 512]); }

  f32x4 acc[4][4] = {};
  short8 af[4][2], b0[2][2], b1[2][2];

  // prologue: tile0 -> buf0, tile1 -> buf1 (12 loads outstanding)
  STG_ALL(0, 0);
  STG_ALL(1, 1);

  int bc = 0;
  for (int kt = 0; kt < 16; ++kt) {
    const int bs = bc >= 1 ? bc - 1 : bc + 2;  // (bc+2)%3
    const int tn = kt + 2 < 16 ? kt + 2 : 15;
    asm volatile("s_waitcnt vmcnt(6)" ::: "memory");
    __builtin_amdgcn_s_barrier();
    __builtin_amdgcn_sched_barrier(0);
    const ushort* Ab = &As[bc][0];
    const ushort* Bb = &Bs[bc][0];
    // ---- all 24 frag reads ----
#pragma unroll
    for (int m = 0; m < 4; m++)
#pragma unroll
      for (int kk = 0; kk < 2; kk++)
        af[m][kk] = ldsrd(Ab, wm * 64 + m * 16 + lr, kk * 64 + g * 16);
#pragma unroll
    for (int n = 0; n < 2; n++)
#pragma unroll
      for (int kk = 0; kk < 2; kk++) {
        b0[n][kk] = ldsrd(Bb, wn * 64 + n * 16 + lr, kk * 64 + g * 16);
        b1[n][kk] = ldsrd(Bb, wn * 64 + 32 + n * 16 + lr, kk * 64 + g * 16);
      }
    // ---- stage tile kt+2 ----
    STG_ALL(bs, tn);
    __builtin_amdgcn_sched_barrier(0);
    asm volatile("s_waitcnt lgkmcnt(0)" ::: "memory");
    __builtin_amdgcn_sched_barrier(0);
    __builtin_amdgcn_s_setprio(1);
#pragma unroll
    for (int m = 0; m < 4; m++)
#pragma unroll
      for (int n = 0; n < 2; n++)
#pragma unroll
        for (int kk = 0; kk < 2; kk++)
          acc[m][n] = __builtin_amdgcn_mfma_f32_16x16x32_bf16(af[m][kk], b0[n][kk],
                                                              acc[m][n], 0, 0, 0);
#pragma unroll
    for (int m = 0; m < 4; m++)
#pragma unroll
      for (int n = 0; n < 2; n++)
#pragma unroll
        for (int kk = 0; kk < 2; kk++)
          acc[m][2 + n] = __builtin_amdgcn_mfma_f32_16x16x32_bf16(af[m][kk], b1[n][kk],
                                                                  acc[m][2 + n], 0, 0, 0);
    __builtin_amdgcn_s_setprio(0);
    __builtin_amdgcn_sched_barrier(0);
    bc = bc + 1 == 3 ? 0 : bc + 1;
  }
#undef STG_ALL

  // ---- epilogue ----
  const int colB = n0 + wn * 64;
#pragma unroll
  for (int m = 0; m < 4; ++m) {
    const int row0 = m0 + wm * 64 + m * 16 + g * 4;
#pragma unroll
    for (int n = 0; n < 4; ++n) {
      const int col = colB + n * 16 + lr;
      if (MODE == 2) {
#pragma unroll
        for (int r = 0; r < 4; r++)
          reinterpret_cast<float*>(O0)[(size_t)(row0 + r) * DM + col] = acc[m][n][r];
      } else if (ysel == 0 || ysel == 1) {
        ushort* O = reinterpret_cast<ushort*>(ysel == 0 ? O0 : O1);
#pragma unroll
        for (int r = 0; r < 4; r++)
          O[(size_t)(row0 + r) * DM + col] = f2b(acc[m][n][r]);
      } else {
        // V transposed: [B][H][DH][S], 4 consecutive s -> ushort4
        const int b = row0 >> 12, s0 = row0 & 4095;
        const int h = col >> 6, dk = col & 63;
        ushort4 o;
        o.x = f2b(acc[m][n][0]); o.y = f2b(acc[m][n][1]);
        o.z = f2b(acc[m][n][2]); o.w = f2b(acc[m][n][3]);
        *reinterpret_cast<ushort4*>(
            reinterpret_cast<ushort*>(O2) +
            (((size_t)(b * NH + h) * DH + dk) << 12) + s0) = o;
      }
    }
  }
}

// ---------------- local attention (window |i-j|<=128) ----------------
// Double-buffered K/V staging with counted vmcnt; raw barriers (no vm drain).
__global__ void attn_local(const ushort* __restrict__ Qp, const ushort* __restrict__ Kp,
                           const ushort* __restrict__ Vt, ushort* __restrict__ Ao) {
  __shared__ ushort Ks[2][4096];
  __shared__ ushort Vs[2][4096];
  __shared__ ushort Ps[4][16 * 72];
  const int tid = threadIdx.x;
  const int lane = tid & 63;
  const int w = tid >> 6;
  const int g = lane >> 4, lr = lane & 15;
  const int bh = blockIdx.y, b = bh >> 4, h = bh & 15;
  const int q0 = blockIdx.x * 64;

  const int qrow = q0 + w * 16 + lr;
  const ushort* qptr = Qp + ((size_t)b * S_LEN + qrow) * DM + h * DH;
  short8 qf[2];
  qf[0] = *reinterpret_cast<const short8*>(qptr + g * 8);
  qf[1] = *reinterpret_cast<const short8*>(qptr + 32 + g * 8);

  float m_r[4], l_r[4];
  f32x4 acc_o[4] = {};
#pragma unroll
  for (int r = 0; r < 4; r++) { m_r[r] = -1e30f; l_r[r] = 0.f; }

  const int sr = tid >> 3;
  const int scb = (tid & 7) * 16;

  const int t_lo = q0 >= 128 ? q0 - 128 : 0;
  const int t_hi = (q0 + 192) <= S_LEN ? (q0 + 192) : S_LEN;

#define STAGE(bb, kk0)                                                        \
  {                                                                           \
    _Pragma("unroll")                                                         \
    for (int i = 0; i < 2; i++) {                                             \
      const int row = i * 32 + sr;                                            \
      const int cbk = scb ^ ((row & 7) << 4);                                 \
      glds16(Kp + ((size_t)b * S_LEN + (kk0) + row) * DM + h * DH + cbk / 2,  \
             &Ks[bb][i * 2048 + w * 512]);                                    \
      glds16(Vt + (((size_t)bh * DH + row) << 12) + (kk0) + cbk / 2,          \
             &Vs[bb][i * 2048 + w * 512]);                                    \
    }                                                                         \
  }

  STAGE(0, t_lo);

  int it = 0;
  for (int k0 = t_lo; k0 < t_hi; k0 += 64, ++it) {
    const int cur = it & 1;
    const bool pf = (k0 + 64 < t_hi);
    if (pf) {
      STAGE(cur ^ 1, k0 + 64);
      asm volatile("s_waitcnt vmcnt(4)" ::: "memory");
    } else {
      asm volatile("s_waitcnt vmcnt(0)" ::: "memory");
    }
    __builtin_amdgcn_sched_barrier(0);
    __builtin_amdgcn_s_barrier();
    __builtin_amdgcn_sched_barrier(0);

    f32x4 sc[4] = {};
#pragma unroll
    for (int kk = 0; kk < 2; kk++) {
#pragma unroll
      for (int nt = 0; nt < 4; nt++) {
        const int kr = nt * 16 + lr;
        const int cbk = (kk * 64 + g * 16) ^ ((kr & 7) << 4);
        short8 kf = *reinterpret_cast<const short8*>(
            reinterpret_cast<const char*>(&Ks[cur][0]) + kr * 128 + cbk);
        sc[nt] = __builtin_amdgcn_mfma_f32_16x16x32_bf16(qf[kk], kf, sc[nt], 0, 0, 0);
      }
    }
    // scale (+ mask only on the 2 edge tiles) + row max
    const bool edge = (k0 < q0 - 64) || (k0 > q0 + 64);
    float mx[4] = {-1e30f, -1e30f, -1e30f, -1e30f};
    if (edge) {
#pragma unroll
      for (int nt = 0; nt < 4; nt++) {
        const int key = k0 + nt * 16 + lr;
#pragma unroll
        for (int r = 0; r < 4; r++) {
          const int qr = q0 + w * 16 + g * 4 + r;
          int d = qr - key; d = d < 0 ? -d : d;
          float s = (d <= 128) ? sc[nt][r] * 0.125f : -1e9f;
          sc[nt][r] = s;
          mx[r] = fmaxf(mx[r], s);
        }
      }
    } else {
#pragma unroll
      for (int nt = 0; nt < 4; nt++)
#pragma unroll
        for (int r = 0; r < 4; r++) {
          const float s = sc[nt][r] * 0.125f;
          sc[nt][r] = s;
          mx[r] = fmaxf(mx[r], s);
        }
    }
#pragma unroll
    for (int r = 0; r < 4; r++) {
      mx[r] = fmaxf(mx[r], __shfl_xor(mx[r], 1));
      mx[r] = fmaxf(mx[r], __shfl_xor(mx[r], 2));
      mx[r] = fmaxf(mx[r], __shfl_xor(mx[r], 4));
      mx[r] = fmaxf(mx[r], __shfl_xor(mx[r], 8));
    }
    float fac[4], rs[4];
#pragma unroll
    for (int r = 0; r < 4; r++) {
      const float mn = fmaxf(m_r[r], mx[r]);
      fac[r] = __expf(m_r[r] - mn);
      m_r[r] = mn;
      rs[r] = 0.f;
    }
#pragma unroll
    for (int nt = 0; nt < 4; nt++)
#pragma unroll
      for (int r = 0; r < 4; r++) {
        const float p = __expf(sc[nt][r] - m_r[r]);
        sc[nt][r] = p;
        rs[r] += p;
      }
#pragma unroll
    for (int r = 0; r < 4; r++) {
      rs[r] += __shfl_xor(rs[r], 1);
      rs[r] += __shfl_xor(rs[r], 2);
      rs[r] += __shfl_xor(rs[r], 4);
      rs[r] += __shfl_xor(rs[r], 8);
      l_r[r] = l_r[r] * fac[r] + rs[r];
    }
#pragma unroll
    for (int nt = 0; nt < 4; nt++)
#pragma unroll
      for (int r = 0; r < 4; r++)
        acc_o[nt][r] *= fac[r];

    ushort* myP = Ps[w];
#pragma unroll
    for (int nt = 0; nt < 4; nt++)
#pragma unroll
      for (int r = 0; r < 4; r++)
        myP[(g * 4 + r) * 72 + nt * 16 + lr] = f2b(sc[nt][r]);
    asm volatile("s_waitcnt lgkmcnt(0)" ::: "memory");
    __builtin_amdgcn_sched_barrier(0);

#pragma unroll
    for (int kk = 0; kk < 2; kk++) {
      short8 pf2 = *reinterpret_cast<const short8*>(myP + lr * 72 + kk * 32 + g * 8);
#pragma unroll
      for (int nt = 0; nt < 4; nt++) {
        const int vr = nt * 16 + lr;
        const int cbk = (kk * 64 + g * 16) ^ ((vr & 7) << 4);
        short8 vf = *reinterpret_cast<const short8*>(
            reinterpret_cast<const char*>(&Vs[cur][0]) + vr * 128 + cbk);
        acc_o[nt] = __builtin_amdgcn_mfma_f32_16x16x32_bf16(pf2, vf, acc_o[nt], 0, 0, 0);
      }
    }
    __builtin_amdgcn_sched_barrier(0);
    __builtin_amdgcn_s_barrier();
    __builtin_amdgcn_sched_barrier(0);
  }
#undef STAGE

  const int qr0 = q0 + w * 16 + g * 4;
  ushort* orow = Ao + (size_t)b * S_LEN * DM + h * DH;
#pragma unroll
  for (int nt = 0; nt < 4; nt++)
#pragma unroll
    for (int r = 0; r < 4; r++)
      orow[(size_t)(qr0 + r) * DM + nt * 16 + lr] = f2b(acc_o[nt][r] / l_r[r]);
}

extern "C" void kernel_launch(void* const* d_in, const int* in_sizes, int n_in,
                              void* d_out, int out_size, void* d_ws, size_t ws_size,
                              hipStream_t stream) {
  const float* q  = (const float*)d_in[0];
  const float* k  = (const float*)d_in[1];
  const float* v  = (const float*)d_in[2];
  const float* wq = (const float*)d_in[3];
  const float* wk = (const float*)d_in[4];
  const float* wv = (const float*)d_in[5];
  const float* wo = (const float*)d_in[6];

  const size_t NX = (size_t)B_SZ * S_LEN * DM;  // 8388608
  const size_t NW = (size_t)DM * DM;            // 1048576
  if (ws_size < (7 * NX + 4 * NW) * sizeof(ushort)) return;

  ushort* ws  = (ushort*)d_ws;
  ushort* qb  = ws;
  ushort* kb  = qb + NX;
  ushort* vb  = kb + NX;
  ushort* wqb = vb + NX;
  ushort* wkb = wqb + NW;
  ushort* wvb = wkb + NW;
  ushort* wob = wvb + NW;
  ushort* Qp  = wob + NW;
  ushort* Kp  = Qp + NX;
  ushort* Vt  = Kp + NX;
  ushort* Ao  = Vt + NX;

  cvt_all<<<dim3(2048), dim3(256), 0, stream>>>(q, k, v, wq, wk, wv, wo, ws);

  gemmP<0><<<dim3(32, 24), dim3(512), 0, stream>>>(qb, kb, vb, wqb, wkb, wvb,
                                                   Qp, Kp, Vt);

  attn_local<<<dim3(64, 32), dim3(256), 0, stream>>>(Qp, Kp, Vt, Ao);

  gemmP<2><<<dim3(32, 8), dim3(512), 0, stream>>>(Ao, Ao, Ao, wob, wob, wob,
                                                  d_out, d_out, d_out);
}

// Round 7
// 154.387 us; speedup vs baseline: 1.2818x; 1.0386x over previous
//
#include <hip/hip_runtime.h>
#include <hip/hip_bf16.h>

#define S_LEN 4096
#define B_SZ 2
#define DM 1024
#define NH 16
#define DH 64

typedef __attribute__((ext_vector_type(8))) short short8;
typedef __attribute__((ext_vector_type(4))) float f32x4;

__device__ __forceinline__ ushort f2b(float f) {
  union { __hip_bfloat16 b; ushort u; } cv;
  cv.b = __float2bfloat16(f);
  return cv.u;
}

__device__ __forceinline__ short8 pack8(float4 a, float4 b) {
  short8 r;
  r[0] = (short)f2b(a.x); r[1] = (short)f2b(a.y);
  r[2] = (short)f2b(a.z); r[3] = (short)f2b(a.w);
  r[4] = (short)f2b(b.x); r[5] = (short)f2b(b.y);
  r[6] = (short)f2b(b.z); r[7] = (short)f2b(b.w);
  return r;
}

__device__ __forceinline__ void glds16(const ushort* g, ushort* l) {
  __builtin_amdgcn_global_load_lds(
      (const __attribute__((address_space(1))) void*)g,
      (__attribute__((address_space(3))) void*)l, 16, 0, 0);
}

// swizzled LDS access: XOR row bits 0-2 into byte-col bits 4-6 (both sides)
__device__ __forceinline__ short8 ldsrd(const ushort* base, int row, int cb) {
  const int pcb = cb ^ ((row & 7) << 4);
  return *reinterpret_cast<const short8*>(
      reinterpret_cast<const char*>(base) + row * 128 + pcb);
}
__device__ __forceinline__ void ldswr(ushort* base, int row, int cb, short8 v) {
  const int pcb = cb ^ ((row & 7) << 4);
  *reinterpret_cast<short8*>(reinterpret_cast<char*>(base) + row * 128 + pcb) = v;
}

// ---------------- weights-only fp32 -> bf16 convert (tiny) ----------------
__global__ void cvt_w(const float* __restrict__ wq, const float* __restrict__ wk,
                      const float* __restrict__ wv, const float* __restrict__ wo,
                      ushort* __restrict__ dst) {
  const int NW4 = 262144;  // 1M/4
  for (int i = blockIdx.x * blockDim.x + threadIdx.x; i < 4 * NW4;
       i += gridDim.x * blockDim.x) {
    const int wsel = i >> 18;
    const int j = i & (NW4 - 1);
    const float* s = wsel == 0 ? wq : wsel == 1 ? wk : wsel == 2 ? wv : wo;
    float4 v = reinterpret_cast<const float4*>(s)[j];
    ushort4 o;
    o.x = f2b(v.x); o.y = f2b(v.y); o.z = f2b(v.z); o.w = f2b(v.w);
    reinterpret_cast<ushort4*>(dst)[i] = o;
  }
}

// ---------------- fused-cvt QKV GEMM ----------------
// C[m][n] = sum_k A[m][k]*W[n][k].  BM=256, BN=128, BK=64, 512 threads.
// A = fp32 (q/k/v): reg-staged (coalesced 8-rows/instr loads -> cvt ->
//   swizzled ds_write_b128), 2 LDS bufs. Write tile t+1 at iter t from regs
//   loaded at t-1 -> compiler emits counted vmcnt(2), never drains.
// W = bf16 (pre-cvt weights): glds16, 3 LDS bufs, explicit vmcnt(10)
//   (waits only loads issued >=2 iters ago; never below 10).
// One barrier + one lgkm drain per K-tile; 32-MFMA uninterrupted run.
// blockIdx.y: y>>3 selects q/k/v; V output written transposed [B][H][DH][S].
__launch_bounds__(512, 1)
__global__ void gemmQKV(const float* __restrict__ Af0, const float* __restrict__ Af1,
                        const float* __restrict__ Af2, const ushort* __restrict__ Wall,
                        ushort* __restrict__ O0, ushort* __restrict__ O1,
                        ushort* __restrict__ O2) {
  __shared__ ushort As[2][16384];  // 256x64 each, 64 KB
  __shared__ ushort Ws[3][8192];   // 128x64 each, 48 KB
  const int tid = threadIdx.x;
  const int lane = tid & 63, w = tid >> 6;
  const int wm = w >> 1, wn = w & 1;
  const int g = lane >> 4, lr = lane & 15;
  const int m0 = blockIdx.x * 256;
  const int ysel = blockIdx.y >> 3;
  const float* A = ysel == 0 ? Af0 : ysel == 1 ? Af1 : Af2;
  const ushort* W = Wall + (size_t)ysel * (DM * DM);
  const int n0 = (blockIdx.y & 7) * 128;

  // A reg-staging geometry: c8 = 16B-bf16 chunk (8 cols), rb = row base
  const int c8 = tid & 7, rb = tid >> 3;  // rb 0..63
  const float* Ab0 = A + (size_t)(m0 + rb) * DM + c8 * 8;
  // W glds16 geometry (pre-swizzled source, round-6 proven)
  const int wcb = ((tid & 7) * 16) ^ ((rb & 7) << 4);
  const ushort* Wsrc = W + (size_t)(n0 + rb) * DM + (wcb >> 1);

  float4 ar[8];

#define LDA(t)                                                                \
  { const int kq = (t) * 64;                                                  \
    _Pragma("unroll")                                                         \
    for (int j = 0; j < 4; j++) {                                             \
      const float* p = Ab0 + (size_t)(64 * j) * DM + kq;                      \
      ar[2 * j] = *reinterpret_cast<const float4*>(p);                        \
      ar[2 * j + 1] = *reinterpret_cast<const float4*>(p + 4);                \
    } }
#define DSWA(b)                                                               \
  { _Pragma("unroll")                                                         \
    for (int j = 0; j < 4; j++)                                               \
      ldswr(As[b], rb + 64 * j, c8 * 16, pack8(ar[2 * j], ar[2 * j + 1])); }
#define STGW(wb, t)                                                           \
  { const int kq = (t) * 64;                                                  \
    glds16(Wsrc + kq, &Ws[wb][w * 512]);                                      \
    glds16(Wsrc + (size_t)64 * DM + kq, &Ws[wb][4096 + w * 512]); }

  f32x4 acc[4][4] = {};
  short8 af[4][2], b0[2][2], b1[2][2];

  // prologue: A tile0 loads first (oldest), then W tiles 0,1, then consume.
  LDA(0);
  STGW(0, 0);
  STGW(1, 1);
  DSWA(0);   // implicit vmcnt(4): waits A(t0), leaves W glds in flight
  LDA(1);
  asm volatile("s_waitcnt lgkmcnt(0)" ::: "memory");
  __builtin_amdgcn_sched_barrier(0);
  __builtin_amdgcn_s_barrier();
  __builtin_amdgcn_sched_barrier(0);

  int wb = 0;   // W buf holding tile kt
  for (int kt = 0; kt < 16; ++kt) {
    const int cur = kt & 1;
    const int wbn = wb >= 1 ? wb - 1 : wb + 2;  // (wb+2)%3
    const int tn = kt + 2 < 16 ? kt + 2 : 15;
    // wait: everything except last iter's 10 issues (8 A-loads + 2 W-glds).
    asm volatile("s_waitcnt vmcnt(10)" ::: "memory");
    __builtin_amdgcn_s_barrier();
    __builtin_amdgcn_sched_barrier(0);
    const ushort* Ab = &As[cur][0];
    const ushort* Bb = &Ws[wb][0];
    // ---- 16 frag reads ----
#pragma unroll
    for (int m = 0; m < 4; m++)
#pragma unroll
      for (int kk = 0; kk < 2; kk++)
        af[m][kk] = ldsrd(Ab, wm * 64 + m * 16 + lr, kk * 64 + g * 16);
#pragma unroll
    for (int n = 0; n < 2; n++)
#pragma unroll
      for (int kk = 0; kk < 2; kk++) {
        b0[n][kk] = ldsrd(Bb, wn * 64 + n * 16 + lr, kk * 64 + g * 16);
        b1[n][kk] = ldsrd(Bb, wn * 64 + 32 + n * 16 + lr, kk * 64 + g * 16);
      }
    // ---- write A tile kt+1 (from regs loaded at kt-1), reload, stage W ----
    DSWA(cur ^ 1);   // implicit counted vmcnt(2) (A-loads precede W-glds)
    LDA(tn);         // A loads first ...
    STGW(wbn, tn);   // ... W glds last (keeps implicit waits counted)
    __builtin_amdgcn_sched_barrier(0);
    asm volatile("s_waitcnt lgkmcnt(0)" ::: "memory");
    __builtin_amdgcn_sched_barrier(0);
    __builtin_amdgcn_s_setprio(1);
#pragma unroll
    for (int m = 0; m < 4; m++)
#pragma unroll
      for (int n = 0; n < 2; n++)
#pragma unroll
        for (int kk = 0; kk < 2; kk++)
          acc[m][n] = __builtin_amdgcn_mfma_f32_16x16x32_bf16(af[m][kk], b0[n][kk],
                                                              acc[m][n], 0, 0, 0);
#pragma unroll
    for (int m = 0; m < 4; m++)
#pragma unroll
      for (int n = 0; n < 2; n++)
#pragma unroll
        for (int kk = 0; kk < 2; kk++)
          acc[m][2 + n] = __builtin_amdgcn_mfma_f32_16x16x32_bf16(af[m][kk], b1[n][kk],
                                                                  acc[m][2 + n], 0, 0, 0);
    __builtin_amdgcn_s_setprio(0);
    __builtin_amdgcn_sched_barrier(0);
    wb = wb + 1 == 3 ? 0 : wb + 1;
  }
#undef LDA
#undef DSWA
#undef STGW

  // ---- epilogue ----
  const int colB = n0 + wn * 64;
#pragma unroll
  for (int m = 0; m < 4; ++m) {
    const int row0 = m0 + wm * 64 + m * 16 + g * 4;
#pragma unroll
    for (int n = 0; n < 4; ++n) {
      const int col = colB + n * 16 + lr;
      if (ysel == 0 || ysel == 1) {
        ushort* O = ysel == 0 ? O0 : O1;
#pragma unroll
        for (int r = 0; r < 4; r++)
          O[(size_t)(row0 + r) * DM + col] = f2b(acc[m][n][r]);
      } else {
        const int b = row0 >> 12, s0 = row0 & 4095;
        const int h = col >> 6, dk = col & 63;
        ushort4 o;
        o.x = f2b(acc[m][n][0]); o.y = f2b(acc[m][n][1]);
        o.z = f2b(acc[m][n][2]); o.w = f2b(acc[m][n][3]);
        *reinterpret_cast<ushort4*>(
            O2 + (((size_t)(b * NH + h) * DH + dk) << 12) + s0) = o;
      }
    }
  }
}

// ---------------- out-projection GEMM (round-6 proven structure) ----------------
// A = Ao bf16, W = wob bf16, out f32. 3-deep glds16 pipeline, vmcnt(6).
__launch_bounds__(512, 2)
__global__ void gemmOut(const ushort* __restrict__ A, const ushort* __restrict__ W,
                        float* __restrict__ Of) {
  __shared__ ushort As[3][16384];
  __shared__ ushort Bs[3][8192];
  const int tid = threadIdx.x;
  const int lane = tid & 63, w = tid >> 6;
  const int wm = w >> 1, wn = w & 1;
  const int g = lane >> 4, lr = lane & 15;
  const int m0 = blockIdx.x * 256;
  const int n0 = blockIdx.y * 128;

  const int row_r = tid >> 3;
  const int cb = ((tid & 7) * 16) ^ ((row_r & 7) << 4);
  const ushort* Asrc = A + (size_t)(m0 + row_r) * DM + (cb >> 1);
  const ushort* Wsrc = W + (size_t)(n0 + row_r) * DM + (cb >> 1);

#define STG_ALL(bs, kt)                                                      \
  { const int kq = (kt) * 64;                                                \
    glds16(Asrc + kq,                        &As[bs][w * 512]);              \
    glds16(Asrc + (size_t)64 * DM + kq,      &As[bs][4096 + w * 512]);       \
    glds16(Asrc + (size_t)128 * DM + kq,     &As[bs][8192 + w * 512]);       \
    glds16(Asrc + (size_t)192 * DM + kq,     &As[bs][12288 + w * 512]);      \
    glds16(Wsrc + kq,                        &Bs[bs][w * 512]);              \
    glds16(Wsrc + (size_t)64 * DM + kq,      &Bs[bs][4096 + w * 512]); }

  f32x4 acc[4][4] = {};
  short8 af[4][2], b0[2][2], b1[2][2];

  STG_ALL(0, 0);
  STG_ALL(1, 1);

  int bc = 0;
  for (int kt = 0; kt < 16; ++kt) {
    const int bs = bc >= 1 ? bc - 1 : bc + 2;
    const int tn = kt + 2 < 16 ? kt + 2 : 15;
    asm volatile("s_waitcnt vmcnt(6)" ::: "memory");
    __builtin_amdgcn_s_barrier();
    __builtin_amdgcn_sched_barrier(0);
    const ushort* Ab = &As[bc][0];
    const ushort* Bb = &Bs[bc][0];
#pragma unroll
    for (int m = 0; m < 4; m++)
#pragma unroll
      for (int kk = 0; kk < 2; kk++)
        af[m][kk] = ldsrd(Ab, wm * 64 + m * 16 + lr, kk * 64 + g * 16);
#pragma unroll
    for (int n = 0; n < 2; n++)
#pragma unroll
      for (int kk = 0; kk < 2; kk++) {
        b0[n][kk] = ldsrd(Bb, wn * 64 + n * 16 + lr, kk * 64 + g * 16);
        b1[n][kk] = ldsrd(Bb, wn * 64 + 32 + n * 16 + lr, kk * 64 + g * 16);
      }
    STG_ALL(bs, tn);
    __builtin_amdgcn_sched_barrier(0);
    asm volatile("s_waitcnt lgkmcnt(0)" ::: "memory");
    __builtin_amdgcn_sched_barrier(0);
    __builtin_amdgcn_s_setprio(1);
#pragma unroll
    for (int m = 0; m < 4; m++)
#pragma unroll
      for (int n = 0; n < 2; n++)
#pragma unroll
        for (int kk = 0; kk < 2; kk++)
          acc[m][n] = __builtin_amdgcn_mfma_f32_16x16x32_bf16(af[m][kk], b0[n][kk],
                                                              acc[m][n], 0, 0, 0);
#pragma unroll
    for (int m = 0; m < 4; m++)
#pragma unroll
      for (int n = 0; n < 2; n++)
#pragma unroll
        for (int kk = 0; kk < 2; kk++)
          acc[m][2 + n] = __builtin_amdgcn_mfma_f32_16x16x32_bf16(af[m][kk], b1[n][kk],
                                                                  acc[m][2 + n], 0, 0, 0);
    __builtin_amdgcn_s_setprio(0);
    __builtin_amdgcn_sched_barrier(0);
    bc = bc + 1 == 3 ? 0 : bc + 1;
  }
#undef STG_ALL

  const int colB = n0 + wn * 64;
#pragma unroll
  for (int m = 0; m < 4; ++m) {
    const int row0 = m0 + wm * 64 + m * 16 + g * 4;
#pragma unroll
    for (int n = 0; n < 4; ++n) {
      const int col = colB + n * 16 + lr;
#pragma unroll
      for (int r = 0; r < 4; r++)
        Of[(size_t)(row0 + r) * DM + col] = acc[m][n][r];
    }
  }
}

// ---------------- local attention (window |i-j|<=128) ----------------
// Double-buffered K/V; ONE barrier per iter: {vmcnt(0); bar; STAGE; compute}.
__global__ void attn_local(const ushort* __restrict__ Qp, const ushort* __restrict__ Kp,
                           const ushort* __restrict__ Vt, ushort* __restrict__ Ao) {
  __shared__ ushort Ks[2][4096];
  __shared__ ushort Vs[2][4096];
  __shared__ ushort Ps[4][16 * 72];
  const int tid = threadIdx.x;
  const int lane = tid & 63;
  const int w = tid >> 6;
  const int g = lane >> 4, lr = lane & 15;
  const int bh = blockIdx.y, b = bh >> 4, h = bh & 15;
  const int q0 = blockIdx.x * 64;

  const int qrow = q0 + w * 16 + lr;
  const ushort* qptr = Qp + ((size_t)b * S_LEN + qrow) * DM + h * DH;
  short8 qf[2];
  qf[0] = *reinterpret_cast<const short8*>(qptr + g * 8);
  qf[1] = *reinterpret_cast<const short8*>(qptr + 32 + g * 8);

  float m_r[4], l_r[4];
  f32x4 acc_o[4] = {};
#pragma unroll
  for (int r = 0; r < 4; r++) { m_r[r] = -1e30f; l_r[r] = 0.f; }

  const int sr = tid >> 3;
  const int scb = (tid & 7) * 16;

  const int t_lo = q0 >= 128 ? q0 - 128 : 0;
  const int t_hi = (q0 + 192) <= S_LEN ? (q0 + 192) : S_LEN;

#define STAGE(bb, kk0)                                                        \
  {                                                                           \
    _Pragma("unroll")                                                         \
    for (int i = 0; i < 2; i++) {                                             \
      const int row = i * 32 + sr;                                            \
      const int cbk = scb ^ ((row & 7) << 4);                                 \
      glds16(Kp + ((size_t)b * S_LEN + (kk0) + row) * DM + h * DH + cbk / 2,  \
             &Ks[bb][i * 2048 + w * 512]);                                    \
      glds16(Vt + (((size_t)bh * DH + row) << 12) + (kk0) + cbk / 2,          \
             &Vs[bb][i * 2048 + w * 512]);                                    \
    }                                                                         \
  }

  STAGE(0, t_lo);

  int it = 0;
  for (int k0 = t_lo; k0 < t_hi; k0 += 64, ++it) {
    const int cur = it & 1;
    // drain own stages for buf[cur]; barrier publishes all waves' DMA writes
    asm volatile("s_waitcnt vmcnt(0)" ::: "memory");
    __builtin_amdgcn_s_barrier();
    __builtin_amdgcn_sched_barrier(0);
    if (k0 + 64 < t_hi) STAGE(cur ^ 1, k0 + 64);
    __builtin_amdgcn_sched_barrier(0);

    f32x4 sc[4] = {};
#pragma unroll
    for (int kk = 0; kk < 2; kk++) {
#pragma unroll
      for (int nt = 0; nt < 4; nt++) {
        const int kr = nt * 16 + lr;
        const int cbk = (kk * 64 + g * 16) ^ ((kr & 7) << 4);
        short8 kf = *reinterpret_cast<const short8*>(
            reinterpret_cast<const char*>(&Ks[cur][0]) + kr * 128 + cbk);
        sc[nt] = __builtin_amdgcn_mfma_f32_16x16x32_bf16(qf[kk], kf, sc[nt], 0, 0, 0);
      }
    }
    const bool edge = (k0 < q0 - 64) || (k0 > q0 + 64);
    float mx[4] = {-1e30f, -1e30f, -1e30f, -1e30f};
    if (edge) {
#pragma unroll
      for (int nt = 0; nt < 4; nt++) {
        const int key = k0 + nt * 16 + lr;
#pragma unroll
        for (int r = 0; r < 4; r++) {
          const int qr = q0 + w * 16 + g * 4 + r;
          int d = qr - key; d = d < 0 ? -d : d;
          float s = (d <= 128) ? sc[nt][r] * 0.125f : -1e9f;
          sc[nt][r] = s;
          mx[r] = fmaxf(mx[r], s);
        }
      }
    } else {
#pragma unroll
      for (int nt = 0; nt < 4; nt++)
#pragma unroll
        for (int r = 0; r < 4; r++) {
          const float s = sc[nt][r] * 0.125f;
          sc[nt][r] = s;
          mx[r] = fmaxf(mx[r], s);
        }
    }
#pragma unroll
    for (int r = 0; r < 4; r++) {
      mx[r] = fmaxf(mx[r], __shfl_xor(mx[r], 1));
      mx[r] = fmaxf(mx[r], __shfl_xor(mx[r], 2));
      mx[r] = fmaxf(mx[r], __shfl_xor(mx[r], 4));
      mx[r] = fmaxf(mx[r], __shfl_xor(mx[r], 8));
    }
    float fac[4], rs[4];
#pragma unroll
    for (int r = 0; r < 4; r++) {
      const float mn = fmaxf(m_r[r], mx[r]);
      fac[r] = __expf(m_r[r] - mn);
      m_r[r] = mn;
      rs[r] = 0.f;
    }
#pragma unroll
    for (int nt = 0; nt < 4; nt++)
#pragma unroll
      for (int r = 0; r < 4; r++) {
        const float p = __expf(sc[nt][r] - m_r[r]);
        sc[nt][r] = p;
        rs[r] += p;
      }
#pragma unroll
    for (int r = 0; r < 4; r++) {
      rs[r] += __shfl_xor(rs[r], 1);
      rs[r] += __shfl_xor(rs[r], 2);
      rs[r] += __shfl_xor(rs[r], 4);
      rs[r] += __shfl_xor(rs[r], 8);
      l_r[r] = l_r[r] * fac[r] + rs[r];
    }
#pragma unroll
    for (int nt = 0; nt < 4; nt++)
#pragma unroll
      for (int r = 0; r < 4; r++)
        acc_o[nt][r] *= fac[r];

    ushort* myP = Ps[w];
#pragma unroll
    for (int nt = 0; nt < 4; nt++)
#pragma unroll
      for (int r = 0; r < 4; r++)
        myP[(g * 4 + r) * 72 + nt * 16 + lr] = f2b(sc[nt][r]);
    asm volatile("s_waitcnt lgkmcnt(0)" ::: "memory");
    __builtin_amdgcn_sched_barrier(0);

#pragma unroll
    for (int kk = 0; kk < 2; kk++) {
      short8 pf2 = *reinterpret_cast<const short8*>(myP + lr * 72 + kk * 32 + g * 8);
#pragma unroll
      for (int nt = 0; nt < 4; nt++) {
        const int vr = nt * 16 + lr;
        const int cbk = (kk * 64 + g * 16) ^ ((vr & 7) << 4);
        short8 vf = *reinterpret_cast<const short8*>(
            reinterpret_cast<const char*>(&Vs[cur][0]) + vr * 128 + cbk);
        acc_o[nt] = __builtin_amdgcn_mfma_f32_16x16x32_bf16(pf2, vf, acc_o[nt], 0, 0, 0);
      }
    }
  }
#undef STAGE

  const int qr0 = q0 + w * 16 + g * 4;
  ushort* orow = Ao + (size_t)b * S_LEN * DM + h * DH;
#pragma unroll
  for (int nt = 0; nt < 4; nt++)
#pragma unroll
    for (int r = 0; r < 4; r++)
      orow[(size_t)(qr0 + r) * DM + nt * 16 + lr] = f2b(acc_o[nt][r] / l_r[r]);
}

extern "C" void kernel_launch(void* const* d_in, const int* in_sizes, int n_in,
                              void* d_out, int out_size, void* d_ws, size_t ws_size,
                              hipStream_t stream) {
  const float* q  = (const float*)d_in[0];
  const float* k  = (const float*)d_in[1];
  const float* v  = (const float*)d_in[2];
  const float* wq = (const float*)d_in[3];
  const float* wk = (const float*)d_in[4];
  const float* wv = (const float*)d_in[5];
  const float* wo = (const float*)d_in[6];

  const size_t NX = (size_t)B_SZ * S_LEN * DM;  // 8388608
  const size_t NW = (size_t)DM * DM;            // 1048576
  if (ws_size < (4 * NX + 4 * NW) * sizeof(ushort)) return;

  ushort* ws  = (ushort*)d_ws;
  ushort* wqb = ws;                 // weights bf16 (contiguous wq,wk,wv,wo)
  ushort* wob = wqb + 3 * NW;
  ushort* Qp  = wqb + 4 * NW;
  ushort* Kp  = Qp + NX;
  ushort* Vt  = Kp + NX;
  ushort* Ao  = Vt + NX;

  cvt_w<<<dim3(2048), dim3(256), 0, stream>>>(wq, wk, wv, wo, wqb);

  gemmQKV<<<dim3(32, 24), dim3(512), 0, stream>>>(q, k, v, wqb, Qp, Kp, Vt);

  attn_local<<<dim3(64, 32), dim3(256), 0, stream>>>(Qp, Kp, Vt, Ao);

  gemmOut<<<dim3(32, 8), dim3(512), 0, stream>>>(Ao, wob, (float*)d_out);
}